// Round 11
// baseline (530.180 us; speedup 1.0000x reference)
//
#include <hip/hip_runtime.h>
#include <stdint.h>

#define T_STEPS 512
#define D_INP   32
#define CHUNK   8
#define NCHUNK  (T_STEPS / CHUNK)

typedef float f2 __attribute__((ext_vector_type(2)));
typedef float f4 __attribute__((ext_vector_type(4)));

typedef const uint32_t __attribute__((address_space(1)))* gas1_t;
typedef uint32_t __attribute__((address_space(3)))* las3_t;

#define LOG2E 1.44269504088896f
#define TANHK (-2.88539008177793f)   // -2*log2(e)

template <int K>
__device__ __forceinline__ float qbcast(float v) {
  return __int_as_float(
      __builtin_amdgcn_mov_dpp(__float_as_int(v), K * 85, 0xF, 0xF, true));
}
template <int CTRL>
__device__ __forceinline__ f2 qrot(f2 v) {
  f2 r;
  r.x = __int_as_float(__builtin_amdgcn_mov_dpp(__float_as_int(v.x), CTRL, 0xF, 0xF, true));
  r.y = __int_as_float(__builtin_amdgcn_mov_dpp(__float_as_int(v.y), CTRL, 0xF, 0xF, true));
  return r;
}
// all-lanes quad sum: rot[1,2,3,0]=0x39 then rot[2,3,0,1]=0x4E
__device__ __forceinline__ f2 qreduce(f2 v) {
  v = v + qrot<0x39>(v);
  v = v + qrot<0x4E>(v);
  return v;
}
__device__ __forceinline__ float frcp(float v) { return __builtin_amdgcn_rcpf(v); }
__device__ __forceinline__ float fexp2(float v) { return __builtin_amdgcn_exp2f(v); }
__device__ __forceinline__ f2 lo2(f4 v) { return __builtin_shufflevector(v, v, 0, 1); }
__device__ __forceinline__ f2 hi2(f4 v) { return __builtin_shufflevector(v, v, 2, 3); }
__device__ __forceinline__ f2 pkfma(f2 a, f2 b, f2 c) {
  return __builtin_elementwise_fma(a, b, c);
}

// Quad-split dots: DS ops/step 18 -> 6. R1-R10 invariant wall (1913
// cyc/step/CU) == 16 elems x 18 DS x ~6.6 cyc = DS-pipe saturation. Lane k
// of each quad reads only its column slice (x[8k:8k+8], h[4k:4k+4]) and
// computes partials for ALL 4 gates of its unit; quad_perm rotate-add tree
// reduces across the quad on the VALU pipe (which has slack); lane then
// selects its own gate. Same 40 pkFMA of math; all LDS reads 4-distinct-
// address conflict-free.
extern "C" __global__ void __launch_bounds__(256)
lstm2_qs(const float* __restrict__ x,
         const float* __restrict__ Wih0, const float* __restrict__ Whh0,
         const float* __restrict__ bih0, const float* __restrict__ bhh0,
         const float* __restrict__ Wih1, const float* __restrict__ Whh1,
         const float* __restrict__ bih1, const float* __restrict__ bhh1,
         const float* __restrict__ fc1w, const float* __restrict__ fc1b,
         const float* __restrict__ fc2w, const float* __restrict__ fc2b,
         float* __restrict__ out)
{
  __shared__ __align__(16) float lx[4][2][CHUNK * D_INP]; // 8KB x staging
  __shared__ __align__(16) float lh0[4][80];
  __shared__ __align__(16) float lh1[4][80];

  const int tid  = threadIdx.x;
  const int w    = tid >> 6;
  const int lane = tid & 63;
  const int b    = (blockIdx.x << 2) + w;

  const int k   = lane & 3;      // own gate: 0=i 1=f 2=g(tanh) 3=o
  const int u   = lane >> 2;     // hidden unit 0..15
  const int row = k * 16 + u;    // own-gate row (bias / activation)

  const float sc = (k == 2) ? -2.0f * LOG2E : -LOG2E;
  const float mA = (k == 2) ?  2.0f : 1.0f;
  const float aA = (k == 2) ? -1.0f : 0.0f;

  // ---- sliced weights: for each gate g, this lane's column slice ----
  // wx[g]: Wih0[g*16+u][8k..8k+8)   (4 f2)   scaled by sc_g
  // wh[g]: Whh0[g*16+u][4k..4k+4)   (2 f2)
  // vi[g]: Wih1[g*16+u][4k..4k+4)   (2 f2)
  // vh[g]: Whh1[g*16+u][4k..4k+4)   (2 f2)
  f2 wx[4][4], wh[4][2], vi[4][2], vh[4][2];
#pragma unroll
  for (int g = 0; g < 4; ++g) {
    const float scg = (g == 2) ? -2.0f * LOG2E : -LOG2E;
    const int r = g * 16 + u;
    const float* p0 = Wih0 + r * 32 + 8 * k;
    f4 va = *(const f4*)(p0);
    f4 vb = *(const f4*)(p0 + 4);
    wx[g][0] = lo2(va) * scg; wx[g][1] = hi2(va) * scg;
    wx[g][2] = lo2(vb) * scg; wx[g][3] = hi2(vb) * scg;
    f4 vc = *(const f4*)(Whh0 + r * 16 + 4 * k);
    wh[g][0] = lo2(vc) * scg; wh[g][1] = hi2(vc) * scg;
    f4 vd = *(const f4*)(Wih1 + r * 16 + 4 * k);
    vi[g][0] = lo2(vd) * scg; vi[g][1] = hi2(vd) * scg;
    f4 ve = *(const f4*)(Whh1 + r * 16 + 4 * k);
    vh[g][0] = lo2(ve) * scg; vh[g][1] = hi2(ve) * scg;
  }
  const float bs0 = sc * (bih0[row] + bhh0[row]);
  const float bs1 = sc * (bih1[row] + bhh1[row]);

  const int slot = (k == 0) ? u : (16 + lane);
  float* h0slot = &lh0[w][slot];
  float* h1slot = &lh1[w][slot];

  float c0 = 0.f, c1 = 0.f;
  f2 h0a = (f2){0.f, 0.f}, h0b = (f2){0.f, 0.f};  // own slice of h0[t-1]
  if (lane < 16) lh1[w][lane] = 0.f;              // h1[t=-1] = 0

  const float* xg = x + (size_t)b * (T_STEPS * D_INP);

  {
    const float* src = xg + lane * 4;
    __builtin_amdgcn_global_load_lds((gas1_t)(const void*)src,
                                     (las3_t)(void*)&lx[w][0][0], 16, 0, 0);
  }

#pragma unroll 1
  for (int c = 0; c < NCHUNK; ++c) {
    asm volatile("s_waitcnt vmcnt(0)" ::: "memory");
    if (c + 1 < NCHUNK) {
      const float* src = xg + (c + 1) * (CHUNK * D_INP) + lane * 4;
      __builtin_amdgcn_global_load_lds((gas1_t)(const void*)src,
                                       (las3_t)(void*)&lx[w][(c + 1) & 1][0],
                                       16, 0, 0);
    }
    const float* xp = &lx[w][c & 1][0];
#pragma unroll
    for (int tt = 0; tt < CHUNK; ++tt) {
      // own slices: x (2 b128), h1[t-1] (1 b128) — 4 distinct addrs each
      const float* xq = xp + tt * D_INP + 8 * k;
      f4 xa = *(const f4*)(xq);
      f4 xb = *(const f4*)(xq + 4);
      f2 x0 = lo2(xa), x1 = hi2(xa), x2 = lo2(xb), x3 = hi2(xb);
      f4 h1v = *(const f4*)(&lh1[w][4 * k]);
      f2 e0 = lo2(h1v), e1 = hi2(h1v);

      // ======== layer 0: partials for all 4 gates over own slice ========
      f2 A0 = wx[0][0] * x0, A1 = wx[1][0] * x0, A2 = wx[2][0] * x0, A3 = wx[3][0] * x0;
      A0 = pkfma(wx[0][1], x1, A0); A1 = pkfma(wx[1][1], x1, A1);
      A2 = pkfma(wx[2][1], x1, A2); A3 = pkfma(wx[3][1], x1, A3);
      A0 = pkfma(wx[0][2], x2, A0); A1 = pkfma(wx[1][2], x2, A1);
      A2 = pkfma(wx[2][2], x2, A2); A3 = pkfma(wx[3][2], x2, A3);
      A0 = pkfma(wx[0][3], x3, A0); A1 = pkfma(wx[1][3], x3, A1);
      A2 = pkfma(wx[2][3], x3, A2); A3 = pkfma(wx[3][3], x3, A3);
      A0 = pkfma(wh[0][0], h0a, A0); A1 = pkfma(wh[1][0], h0a, A1);
      A2 = pkfma(wh[2][0], h0a, A2); A3 = pkfma(wh[3][0], h0a, A3);
      A0 = pkfma(wh[0][1], h0b, A0); A1 = pkfma(wh[1][1], h0b, A1);
      A2 = pkfma(wh[2][1], h0b, A2); A3 = pkfma(wh[3][1], h0b, A3);
      A0 = qreduce(A0); A1 = qreduce(A1); A2 = qreduce(A2); A3 = qreduce(A3);
      f2 t01 = (k & 1) ? A1 : A0;
      f2 t23 = (k & 1) ? A3 : A2;
      f2 ownA = (k & 2) ? t23 : t01;
      float gs = ownA.x + ownA.y + bs0;
      float av = fmaf(mA, frcp(1.f + fexp2(gs)), aA);
      float fv = qbcast<1>(av), gv = qbcast<2>(av), ov = qbcast<3>(av);
      c0 = fmaf(fv, c0, av * gv);
      float th = fmaf(2.f, frcp(1.f + fexp2(TANHK * c0)), -1.f);
      float h0n = ov * th;
      *h0slot = h0n;
      // read back own h0[t] slice (1 b128)
      f4 h0v = *(const f4*)(&lh0[w][4 * k]);
      h0a = lo2(h0v); h0b = hi2(h0v);

      // ======== layer 1: partials over own slice ========
      f2 B0 = vi[0][0] * h0a, B1 = vi[1][0] * h0a, B2 = vi[2][0] * h0a, B3 = vi[3][0] * h0a;
      B0 = pkfma(vi[0][1], h0b, B0); B1 = pkfma(vi[1][1], h0b, B1);
      B2 = pkfma(vi[2][1], h0b, B2); B3 = pkfma(vi[3][1], h0b, B3);
      B0 = pkfma(vh[0][0], e0, B0); B1 = pkfma(vh[1][0], e0, B1);
      B2 = pkfma(vh[2][0], e0, B2); B3 = pkfma(vh[3][0], e0, B3);
      B0 = pkfma(vh[0][1], e1, B0); B1 = pkfma(vh[1][1], e1, B1);
      B2 = pkfma(vh[2][1], e1, B2); B3 = pkfma(vh[3][1], e1, B3);
      B0 = qreduce(B0); B1 = qreduce(B1); B2 = qreduce(B2); B3 = qreduce(B3);
      f2 s01 = (k & 1) ? B1 : B0;
      f2 s23 = (k & 1) ? B3 : B2;
      f2 ownB = (k & 2) ? s23 : s01;
      float gs1 = ownB.x + ownB.y + bs1;
      float av1 = fmaf(mA, frcp(1.f + fexp2(gs1)), aA);
      float fv1 = qbcast<1>(av1), gv1 = qbcast<2>(av1), ov1 = qbcast<3>(av1);
      c1 = fmaf(fv1, c1, av1 * gv1);
      float th1 = fmaf(2.f, frcp(1.f + fexp2(TANHK * c1)), -1.f);
      float h1n = ov1 * th1;
      *h1slot = h1n;
    }
  }

  // ======== head: y = relu(h1_T @ fc1^T + b1) @ fc2^T + b2 ========
  float h1f[16];
#pragma unroll
  for (int q = 0; q < 4; ++q) {
    f4 hv = *(const f4*)(&lh1[w][4 * q]);
#pragma unroll
    for (int r = 0; r < 4; ++r) h1f[4 * q + r] = hv[r];
  }
  float rr = 0.f;
  if (lane < 8) {
    float acc = fc1b[lane];
#pragma unroll
    for (int j = 0; j < 16; ++j) acc = fmaf(fc1w[lane * 16 + j], h1f[j], acc);
    rr = fmaxf(acc, 0.f) * fc2w[lane];
  }
  rr += __shfl_xor(rr, 1, 64);
  rr += __shfl_xor(rr, 2, 64);
  rr += __shfl_xor(rr, 4, 64);
  if (lane == 0) out[b] = rr + fc2b[0];
}

extern "C" void kernel_launch(void* const* d_in, const int* in_sizes, int n_in,
                              void* d_out, int out_size, void* d_ws, size_t ws_size,
                              hipStream_t stream) {
  (void)in_sizes; (void)n_in; (void)d_ws; (void)ws_size; (void)out_size;
  const float* x    = (const float*)d_in[0];
  const float* Wih0 = (const float*)d_in[1];
  const float* Whh0 = (const float*)d_in[2];
  const float* bih0 = (const float*)d_in[3];
  const float* bhh0 = (const float*)d_in[4];
  const float* Wih1 = (const float*)d_in[5];
  const float* Whh1 = (const float*)d_in[6];
  const float* bih1 = (const float*)d_in[7];
  const float* bhh1 = (const float*)d_in[8];
  const float* fc1w = (const float*)d_in[9];
  const float* fc1b = (const float*)d_in[10];
  const float* fc2w = (const float*)d_in[11];
  const float* fc2b = (const float*)d_in[12];
  lstm2_qs<<<dim3(1024), dim3(256), 0, stream>>>(
      x, Wih0, Whh0, bih0, bhh0, Wih1, Whh1, bih1, bhh1,
      fc1w, fc1b, fc2w, fc2b, (float*)d_out);
}